// Round 2
// baseline (487.490 us; speedup 1.0000x reference)
//
#include <hip/hip_runtime.h>

#define N_NODES 100000
#define N_EDGES 1600000
// IN=128, HID=128, OUT=2

__device__ __forceinline__ int clamp_idx(int v) {
  return v < 0 ? 0 : (v >= N_NODES ? N_NODES - 1 : v);
}

// ---------------- CSR build ----------------

__global__ __launch_bounds__(256) void count_kernel(const int* __restrict__ dst,
                                                    int* __restrict__ counts) {
  int e = blockIdx.x * 256 + threadIdx.x;
  if (e < N_EDGES) atomicAdd(&counts[clamp_idx(dst[e])], 1);
}

// Per node: deg_inv_sqrt, segment reservation (order-free exclusive offsets via atomic).
__global__ __launch_bounds__(256) void node_kernel(const int* __restrict__ counts,
                                                   float* __restrict__ dis,
                                                   int* __restrict__ row_start,
                                                   int* __restrict__ cursor,
                                                   int* __restrict__ total) {
  int d = blockIdx.x * 256 + threadIdx.x;
  if (d < N_NODES) {
    int c = counts[d];
    dis[d] = rsqrtf((float)c + 1.0f);
    int st = atomicAdd(total, c);
    row_start[d] = st;
    cursor[d] = st;
  }
}

__global__ __launch_bounds__(256) void scatter_kernel(const int* __restrict__ src,
                                                      const int* __restrict__ dst,
                                                      const float* __restrict__ dis,
                                                      int* __restrict__ cursor,
                                                      int* __restrict__ src_sorted,
                                                      float* __restrict__ norm_sorted) {
  int e = blockIdx.x * 256 + threadIdx.x;
  if (e < N_EDGES) {
    int s = clamp_idx(src[e]), d = clamp_idx(dst[e]);
    int pos = atomicAdd(&cursor[d], 1);
    if (pos >= 0 && pos < N_EDGES) {
      src_sorted[pos] = s;
      norm_sorted[pos] = dis[s] * dis[d];
    }
  }
}

// ---------------- GEMM: xw = x @ W1  (fp32 vector, K-tiled LDS) ----------------
// Block: 256 threads -> 32 rows x 128 cols, thread = 4 rows x 4 cols.
__global__ __launch_bounds__(256) void gemm_xw(const float* __restrict__ x,
                                               const float* __restrict__ Wg,
                                               float* __restrict__ xw) {
  __shared__ float Wl[32 * 128];   // 16 KB : one K-slab of W1
  __shared__ float Xl[32 * 36];    // padded rows (36) to break bank patterns
  int t = threadIdx.x;
  int r0 = blockIdx.x * 32;        // 100000 = 32 * 3125 exactly
  int tx = t & 31, ty = t >> 5;
  float acc[4][4] = {};

  for (int kb = 0; kb < 4; ++kb) {
    __syncthreads();
    // stage W slab: 32x128 floats = 1024 float4, 4 per thread, coalesced
#pragma unroll
    for (int i = 0; i < 4; ++i) {
      int f = (i * 256 + t) * 4;
      *(float4*)&Wl[f] = *(const float4*)&Wg[kb * 32 * 128 + f];
    }
    // stage X slab: 32 rows x 32 k, 1 float4 per thread
    {
      int row = t >> 3, kk = (t & 7) * 4;
      float4 v = *(const float4*)&x[(r0 + row) * 128 + kb * 32 + kk];
      Xl[row * 36 + kk + 0] = v.x;
      Xl[row * 36 + kk + 1] = v.y;
      Xl[row * 36 + kk + 2] = v.z;
      Xl[row * 36 + kk + 3] = v.w;
    }
    __syncthreads();
#pragma unroll
    for (int k = 0; k < 32; ++k) {
      float4 wv = *(float4*)&Wl[k * 128 + tx * 4];
#pragma unroll
      for (int i = 0; i < 4; ++i) {
        float xv = Xl[(ty * 4 + i) * 36 + k];
        acc[i][0] += xv * wv.x;
        acc[i][1] += xv * wv.y;
        acc[i][2] += xv * wv.z;
        acc[i][3] += xv * wv.w;
      }
    }
  }
#pragma unroll
  for (int i = 0; i < 4; ++i) {
    *(float4*)&xw[(r0 + ty * 4 + i) * 128 + tx * 4] =
        make_float4(acc[i][0], acc[i][1], acc[i][2], acc[i][3]);
  }
}

// ---------------- Layer-1 aggregation fused with (h @ W2) ----------------
// Wave per dst node. Lane owns 2 channels. Per edge: coalesced 512B read of xw[src].
// Epilogue: self-loop + bias + relu, then project 128->2 with W2 in-register and
// wave-reduce; stores only hw[node][2]. h is never materialized.
__global__ __launch_bounds__(256) void agg1_kernel(const float* __restrict__ xw,
                                                   const float* __restrict__ b1,
                                                   const float* __restrict__ W2,
                                                   const float* __restrict__ dis,
                                                   const int* __restrict__ row_start,
                                                   const int* __restrict__ counts,
                                                   const int* __restrict__ src_sorted,
                                                   const float* __restrict__ norm_sorted,
                                                   float* __restrict__ hw) {
  int wid = blockIdx.x * 4 + (threadIdx.x >> 6);
  if (wid >= N_NODES) return;
  int lane = threadIdx.x & 63;
  int c = lane * 2;
  int start = row_start[wid];
  int cnt = counts[wid];
  float a0 = 0.f, a1 = 0.f;
  int i = 0;
  // 2-deep manual unroll so two gathers are in flight
  for (; i + 2 <= cnt; i += 2) {
    int e = start + i;
    int s0 = src_sorted[e], s1 = src_sorted[e + 1];
    float n0 = norm_sorted[e], n1 = norm_sorted[e + 1];
    float2 v0 = *(const float2*)&xw[s0 * 128 + c];
    float2 v1 = *(const float2*)&xw[s1 * 128 + c];
    a0 += v0.x * n0 + v1.x * n1;
    a1 += v0.y * n0 + v1.y * n1;
  }
  if (i < cnt) {
    int e = start + i;
    int s0 = src_sorted[e];
    float n0 = norm_sorted[e];
    float2 v0 = *(const float2*)&xw[s0 * 128 + c];
    a0 += v0.x * n0;
    a1 += v0.y * n0;
  }
  float ds = dis[wid];
  float dsq = ds * ds;
  float2 vd = *(const float2*)&xw[wid * 128 + c];
  a0 += vd.x * dsq + b1[c];
  a1 += vd.y * dsq + b1[c + 1];
  a0 = fmaxf(a0, 0.f);
  a1 = fmaxf(a1, 0.f);
  // h row (in-register) @ W2 -> 2 outputs; W2 is [128][2] row-major
  float w00 = W2[c * 2 + 0], w01 = W2[c * 2 + 1];
  float w10 = W2[(c + 1) * 2 + 0], w11 = W2[(c + 1) * 2 + 1];
  float p0 = a0 * w00 + a1 * w10;
  float p1 = a0 * w01 + a1 * w11;
#pragma unroll
  for (int off = 32; off >= 1; off >>= 1) {
    p0 += __shfl_xor(p0, off);
    p1 += __shfl_xor(p1, off);
  }
  if (lane == 0) *(float2*)&hw[wid * 2] = make_float2(p0, p1);
}

// ---------------- Layer-2 aggregation (2 channels) ----------------
// Wave per dst; lanes stride over edges; 8B L2-resident gathers; shuffle-reduce.
__global__ __launch_bounds__(256) void agg2_kernel(const float* __restrict__ hw,
                                                   const float* __restrict__ b2,
                                                   const float* __restrict__ dis,
                                                   const int* __restrict__ row_start,
                                                   const int* __restrict__ counts,
                                                   const int* __restrict__ src_sorted,
                                                   const float* __restrict__ norm_sorted,
                                                   float* __restrict__ out) {
  int wid = blockIdx.x * 4 + (threadIdx.x >> 6);
  if (wid >= N_NODES) return;
  int lane = threadIdx.x & 63;
  int start = row_start[wid];
  int cnt = counts[wid];
  float a0 = 0.f, a1 = 0.f;
  for (int i = lane; i < cnt; i += 64) {
    int e = start + i;
    int s = src_sorted[e];
    float n = norm_sorted[e];
    float2 v = *(const float2*)&hw[s * 2];
    a0 += v.x * n;
    a1 += v.y * n;
  }
#pragma unroll
  for (int off = 32; off >= 1; off >>= 1) {
    a0 += __shfl_xor(a0, off);
    a1 += __shfl_xor(a1, off);
  }
  if (lane == 0) {
    float ds = dis[wid];
    float dsq = ds * ds;
    float2 vd = *(const float2*)&hw[wid * 2];
    out[wid * 2 + 0] = a0 + vd.x * dsq + b2[0];
    out[wid * 2 + 1] = a1 + vd.y * dsq + b2[1];
  }
}

// ---------------- launch ----------------

extern "C" void kernel_launch(void* const* d_in, const int* in_sizes, int n_in,
                              void* d_out, int out_size, void* d_ws, size_t ws_size,
                              hipStream_t stream) {
  const float* x  = (const float*)d_in[0];
  const int*   ei = (const int*)d_in[1];
  const float* W1 = (const float*)d_in[2];
  const float* b1 = (const float*)d_in[3];
  const float* W2 = (const float*)d_in[4];
  const float* b2 = (const float*)d_in[5];
  float* out = (float*)d_out;

  const int* src = ei;            // edge_index[0]
  const int* dst = ei + N_EDGES;  // edge_index[1]

  char* ws = (char*)d_ws;
  size_t off = 0;
  auto walloc = [&](size_t bytes) -> void* {
    void* p = ws + off;
    off += (bytes + 255) & ~(size_t)255;
    return p;
  };
  float* xw          = (float*)walloc((size_t)N_NODES * 128 * 4);  // 51.2 MB
  int*   counts      = (int*)walloc((size_t)N_NODES * 4);
  int*   row_start   = (int*)walloc((size_t)N_NODES * 4);
  int*   cursor      = (int*)walloc((size_t)N_NODES * 4);
  float* dis         = (float*)walloc((size_t)N_NODES * 4);
  int*   total       = (int*)walloc(256);
  int*   src_sorted  = (int*)walloc((size_t)N_EDGES * 4);
  float* norm_sorted = (float*)walloc((size_t)N_EDGES * 4);
  float* hw          = (float*)walloc((size_t)N_NODES * 2 * 4);

  if (off > ws_size) return;  // workspace too small: fail visibly, don't corrupt memory

  hipMemsetAsync(counts, 0, (size_t)N_NODES * 4, stream);
  hipMemsetAsync(total, 0, 4, stream);

  count_kernel<<<(N_EDGES + 255) / 256, 256, 0, stream>>>(dst, counts);
  node_kernel<<<(N_NODES + 255) / 256, 256, 0, stream>>>(counts, dis, row_start, cursor, total);
  scatter_kernel<<<(N_EDGES + 255) / 256, 256, 0, stream>>>(src, dst, dis, cursor,
                                                            src_sorted, norm_sorted);
  gemm_xw<<<N_NODES / 32, 256, 0, stream>>>(x, W1, xw);
  agg1_kernel<<<(N_NODES + 3) / 4, 256, 0, stream>>>(xw, b1, W2, dis, row_start, counts,
                                                     src_sorted, norm_sorted, hw);
  agg2_kernel<<<(N_NODES + 3) / 4, 256, 0, stream>>>(hw, b2, dis, row_start, counts,
                                                     src_sorted, norm_sorted, out);
}

// Round 5
// 428.517 us; speedup vs baseline: 1.1376x; 1.1376x over previous
//
#include <hip/hip_runtime.h>

#define N_NODES 100000
#define N_EDGES 1600000
// IN=128, HID=128, OUT=2

__device__ __forceinline__ int clamp_idx(int v) {
  return v < 0 ? 0 : (v >= N_NODES ? N_NODES - 1 : v);
}

__device__ __forceinline__ unsigned short f2bf(float f) {
  unsigned u = __float_as_uint(f);
  unsigned r = ((u >> 16) & 1u) + 0x7fffu;  // round-to-nearest-even
  return (unsigned short)((u + r) >> 16);
}
__device__ __forceinline__ float bf_lo(unsigned u) {  // low 16 bits as bf16
  return __uint_as_float(u << 16);
}
__device__ __forceinline__ float bf_hi(unsigned u) {  // high 16 bits as bf16
  return __uint_as_float(u & 0xffff0000u);
}

// ---------------- CSR build ----------------

__global__ __launch_bounds__(256) void count_kernel(const int* __restrict__ dst,
                                                    int* __restrict__ counts) {
  int e = blockIdx.x * 256 + threadIdx.x;
  if (e < N_EDGES) atomicAdd(&counts[clamp_idx(dst[e])], 1);
}

__global__ __launch_bounds__(256) void node_kernel(const int* __restrict__ counts,
                                                   float* __restrict__ dis,
                                                   int* __restrict__ row_start,
                                                   int* __restrict__ cursor,
                                                   int* __restrict__ total) {
  int d = blockIdx.x * 256 + threadIdx.x;
  if (d < N_NODES) {
    int c = counts[d];
    dis[d] = rsqrtf((float)c + 1.0f);
    int st = atomicAdd(total, c);
    row_start[d] = st;
    cursor[d] = st;
  }
}

// Writes fused edge record: {src, norm-as-bits}
__global__ __launch_bounds__(256) void scatter_kernel(const int* __restrict__ src,
                                                      const int* __restrict__ dst,
                                                      const float* __restrict__ dis,
                                                      int* __restrict__ cursor,
                                                      int2* __restrict__ erec) {
  int e = blockIdx.x * 256 + threadIdx.x;
  if (e < N_EDGES) {
    int s = clamp_idx(src[e]), d = clamp_idx(dst[e]);
    int pos = atomicAdd(&cursor[d], 1);
    if (pos >= 0 && pos < N_EDGES) {
      erec[pos] = make_int2(s, __float_as_int(dis[s] * dis[d]));
    }
  }
}

// ---------------- GEMM: xwb = bf16(x @ W1)  (fp32 vector compute) ----------------
// Block 256 -> 32 rows x 128 cols, thread = 4 rows x 4 cols. Both LDS operands read
// as float4 (X tile stored k-major so 4 rows of same k are contiguous).
// Output row = 128 bf16 = 64 uints (stride 64!).
__global__ __launch_bounds__(256) void gemm_xw(const float* __restrict__ x,
                                               const float* __restrict__ Wg,
                                               unsigned int* __restrict__ xwb) {
  __shared__ float Wl[32 * 128];   // k-slab of W1: [k][128]
  __shared__ float Xlt[32 * 36];   // transposed X slab: [k][row], padded
  int t = threadIdx.x;
  int r0 = blockIdx.x * 32;        // 100000 = 32 * 3125 exactly
  int tx = t & 31, ty = t >> 5;
  float acc[4][4] = {};

  for (int kb = 0; kb < 4; ++kb) {
    __syncthreads();
#pragma unroll
    for (int i = 0; i < 4; ++i) {
      int f = (i * 256 + t) * 4;
      *(float4*)&Wl[f] = *(const float4*)&Wg[kb * 32 * 128 + f];
    }
    {
      int row = t >> 3, kk = (t & 7) * 4;
      float4 v = *(const float4*)&x[(r0 + row) * 128 + kb * 32 + kk];
      Xlt[(kk + 0) * 36 + row] = v.x;
      Xlt[(kk + 1) * 36 + row] = v.y;
      Xlt[(kk + 2) * 36 + row] = v.z;
      Xlt[(kk + 3) * 36 + row] = v.w;
    }
    __syncthreads();
#pragma unroll
    for (int k = 0; k < 32; ++k) {
      float4 wv = *(float4*)&Wl[k * 128 + tx * 4];
      float4 xv = *(float4*)&Xlt[k * 36 + ty * 4];
      float xr[4] = {xv.x, xv.y, xv.z, xv.w};
#pragma unroll
      for (int i = 0; i < 4; ++i) {
        acc[i][0] += xr[i] * wv.x;
        acc[i][1] += xr[i] * wv.y;
        acc[i][2] += xr[i] * wv.z;
        acc[i][3] += xr[i] * wv.w;
      }
    }
  }
  // pack 4 cols -> uint2 (4 bf16), one store per row; row stride = 64 uints
#pragma unroll
  for (int i = 0; i < 4; ++i) {
    unsigned lo = ((unsigned)f2bf(acc[i][1]) << 16) | f2bf(acc[i][0]);
    unsigned hi = ((unsigned)f2bf(acc[i][3]) << 16) | f2bf(acc[i][2]);
    int row = r0 + ty * 4 + i;
    *(uint2*)&xwb[row * 64 + tx * 2] = make_uint2(lo, hi);
  }
}

// ---------------- Layer-1 aggregation (bf16 rows) fused with (h @ W2) ----------------
// Wave per dst node. 2 edges per load instruction: half = lane>>5 picks the edge,
// sublane = lane&31 owns 4 channels (one uint2 = 8B). 4-deep unroll -> 8 edges/wave
// in flight. Row = 32 uint2 (256 B).
__global__ __launch_bounds__(256) void agg1_kernel(const unsigned int* __restrict__ xwb,
                                                   const float* __restrict__ b1,
                                                   const float* __restrict__ W2,
                                                   const float* __restrict__ dis,
                                                   const int* __restrict__ row_start,
                                                   const int* __restrict__ counts,
                                                   const int2* __restrict__ erec,
                                                   float* __restrict__ hw) {
  int wid = blockIdx.x * 4 + (threadIdx.x >> 6);
  if (wid >= N_NODES) return;
  int lane = threadIdx.x & 63;
  int half = lane >> 5;
  int sub = lane & 31;
  int c = sub * 4;                        // this lane's 4 channels
  int start = row_start[wid];
  int cnt = counts[wid];
  const uint2* xw2 = (const uint2*)xwb;   // row = node*32 uint2 (256B/row)

  float a0 = 0.f, a1 = 0.f, a2 = 0.f, a3 = 0.f;

  for (int i = 0; i < cnt; i += 8) {
#pragma unroll
    for (int k = 0; k < 4; ++k) {
      int ei = i + 2 * k + half;
      bool valid = ei < cnt;
      int2 rec = erec[valid ? (start + ei) : 0];
      float n = valid ? __int_as_float(rec.y) : 0.0f;
      uint2 g = xw2[rec.x * 32 + sub];
      a0 += bf_lo(g.x) * n;
      a1 += bf_hi(g.x) * n;
      a2 += bf_lo(g.y) * n;
      a3 += bf_hi(g.y) * n;
    }
  }
  // combine the two edge-halves: lanes l and l+32 hold partial sums of same channels
  a0 += __shfl_xor(a0, 32);
  a1 += __shfl_xor(a1, 32);
  a2 += __shfl_xor(a2, 32);
  a3 += __shfl_xor(a3, 32);

  float ds = dis[wid];
  float dsq = ds * ds;
  uint2 gs = xw2[wid * 32 + sub];
  float4 bv = *(const float4*)&b1[c];
  a0 += bf_lo(gs.x) * dsq + bv.x;
  a1 += bf_hi(gs.x) * dsq + bv.y;
  a2 += bf_lo(gs.y) * dsq + bv.z;
  a3 += bf_hi(gs.y) * dsq + bv.w;
  a0 = fmaxf(a0, 0.f); a1 = fmaxf(a1, 0.f);
  a2 = fmaxf(a2, 0.f); a3 = fmaxf(a3, 0.f);

  // project 4 channels -> 2 outputs: W2 rows c..c+3 are 8 consecutive floats
  float4 w01 = *(const float4*)&W2[c * 2];      // rows c, c+1
  float4 w23 = *(const float4*)&W2[c * 2 + 4];  // rows c+2, c+3
  float p0 = a0 * w01.x + a1 * w01.z + a2 * w23.x + a3 * w23.z;
  float p1 = a0 * w01.y + a1 * w01.w + a2 * w23.y + a3 * w23.w;
#pragma unroll
  for (int off = 16; off >= 1; off >>= 1) {
    p0 += __shfl_xor(p0, off);
    p1 += __shfl_xor(p1, off);
  }
  if (lane == 0) *(float2*)&hw[wid * 2] = make_float2(p0, p1);
}

// ---------------- Layer-2 aggregation (2 channels) ----------------
__global__ __launch_bounds__(256) void agg2_kernel(const float* __restrict__ hw,
                                                   const float* __restrict__ b2,
                                                   const float* __restrict__ dis,
                                                   const int* __restrict__ row_start,
                                                   const int* __restrict__ counts,
                                                   const int2* __restrict__ erec,
                                                   float* __restrict__ out) {
  int wid = blockIdx.x * 4 + (threadIdx.x >> 6);
  if (wid >= N_NODES) return;
  int lane = threadIdx.x & 63;
  int start = row_start[wid];
  int cnt = counts[wid];
  float a0 = 0.f, a1 = 0.f;
  for (int i = lane; i < cnt; i += 64) {
    int2 rec = erec[start + i];
    float n = __int_as_float(rec.y);
    float2 v = *(const float2*)&hw[rec.x * 2];
    a0 += v.x * n;
    a1 += v.y * n;
  }
#pragma unroll
  for (int off = 32; off >= 1; off >>= 1) {
    a0 += __shfl_xor(a0, off);
    a1 += __shfl_xor(a1, off);
  }
  if (lane == 0) {
    float ds = dis[wid];
    float dsq = ds * ds;
    float2 vd = *(const float2*)&hw[wid * 2];
    out[wid * 2 + 0] = a0 + vd.x * dsq + b2[0];
    out[wid * 2 + 1] = a1 + vd.y * dsq + b2[1];
  }
}

// ---------------- launch ----------------

extern "C" void kernel_launch(void* const* d_in, const int* in_sizes, int n_in,
                              void* d_out, int out_size, void* d_ws, size_t ws_size,
                              hipStream_t stream) {
  const float* x  = (const float*)d_in[0];
  const int*   ei = (const int*)d_in[1];
  const float* W1 = (const float*)d_in[2];
  const float* b1 = (const float*)d_in[3];
  const float* W2 = (const float*)d_in[4];
  const float* b2 = (const float*)d_in[5];
  float* out = (float*)d_out;

  const int* src = ei;            // edge_index[0]
  const int* dst = ei + N_EDGES;  // edge_index[1]

  char* ws = (char*)d_ws;
  size_t off = 0;
  auto walloc = [&](size_t bytes) -> void* {
    void* p = ws + off;
    off += (bytes + 255) & ~(size_t)255;
    return p;
  };
  unsigned int* xwb  = (unsigned int*)walloc((size_t)N_NODES * 128 * 2);  // 25.6 MB bf16
  int*   counts      = (int*)walloc((size_t)N_NODES * 4);
  int*   row_start   = (int*)walloc((size_t)N_NODES * 4);
  int*   cursor      = (int*)walloc((size_t)N_NODES * 4);
  float* dis         = (float*)walloc((size_t)N_NODES * 4);
  int*   total       = (int*)walloc(256);
  int2*  erec        = (int2*)walloc((size_t)N_EDGES * 8);                // 12.8 MB
  float* hw          = (float*)walloc((size_t)N_NODES * 2 * 4);

  if (off > ws_size) return;  // workspace too small: fail visibly, don't corrupt memory

  hipMemsetAsync(counts, 0, (size_t)N_NODES * 4, stream);
  hipMemsetAsync(total, 0, 4, stream);

  count_kernel<<<(N_EDGES + 255) / 256, 256, 0, stream>>>(dst, counts);
  node_kernel<<<(N_NODES + 255) / 256, 256, 0, stream>>>(counts, dis, row_start, cursor, total);
  scatter_kernel<<<(N_EDGES + 255) / 256, 256, 0, stream>>>(src, dst, dis, cursor, erec);
  gemm_xw<<<N_NODES / 32, 256, 0, stream>>>(x, W1, xwb);
  agg1_kernel<<<(N_NODES + 3) / 4, 256, 0, stream>>>(xwb, b1, W2, dis, row_start, counts,
                                                     erec, hw);
  agg2_kernel<<<(N_NODES + 3) / 4, 256, 0, stream>>>(hw, b2, dis, row_start, counts,
                                                     erec, out);
}